// Round 6
// baseline (178.170 us; speedup 1.0000x reference)
//
#include <hip/hip_runtime.h>

#define BN_EPS 1e-3f
#define STATC  32   // spread copies for the stats atomics
#define MBLK   128  // merge tile: slots per block

using bfrag  = __attribute__((ext_vector_type(8))) short;  // 8 bf16 (4 VGPRs)
using f32x4v = __attribute__((ext_vector_type(4))) float;  // native vec for NT builtins

__device__ __forceinline__ unsigned short f2bf(float f) {
    union { float f; unsigned u; } v; v.f = f;
    unsigned r = v.u + 0x7FFFu + ((v.u >> 16) & 1u);   // RNE
    return (unsigned short)(r >> 16);
}

// ---------------------------------------------------------------------------
// Tiny prep: weight fragments + zero stats. 4352 threads.
//  W: W0/W1 [27,16,16] -> Wb0/Wb1 MFMA B-frag order (14 K-steps)
//  F: Wf [16,128] -> Wfb B-frag order (8 col-tiles, K=16 padded to 32)
//  Z: zero 2*STATC*32 spread stat accumulators
// ---------------------------------------------------------------------------
__global__ __launch_bounds__(256)
void prep_kernel(const float* __restrict__ W0, const float* __restrict__ W1,
                 const float* __restrict__ Wf,
                 unsigned short* __restrict__ Wb0, unsigned short* __restrict__ Wb1,
                 unsigned short* __restrict__ Wfb,
                 float* __restrict__ stats)
{
    int t = blockIdx.x * 256 + threadIdx.x;
    unsigned short tmp[8];
    if (t < 2 * 14 * 64) {                // Wb0 / Wb1
        int w = t >= 896;
        int l = t - w * 896;
        int s = l >> 6, lane = l & 63;
        int q = lane >> 4, n = lane & 15;
        int tap = 2 * s + (q >> 1);
        int cb  = (q & 1) * 8;
        const float* W = w ? W1 : W0;
        unsigned short* Wb = w ? Wb1 : Wb0;
#pragma unroll
        for (int j = 0; j < 8; ++j)
            tmp[j] = (tap < 27) ? f2bf(W[((size_t)(tap * 16 + cb + j)) * 16 + n]) : 0;
        *(int4*)(Wb + (size_t)l * 8) = *(int4*)tmp;
        return;
    }
    t -= 2 * 14 * 64;
    if (t < 512) {                        // Wfb: B[k=q*8+j][ct*16+n], k>=16 -> 0
        int ct = t >> 6, lane = t & 63;
        int q = lane >> 4, n = lane & 15;
#pragma unroll
        for (int j = 0; j < 8; ++j)
            tmp[j] = (q < 2) ? f2bf(Wf[(size_t)(q * 8 + j) * 128 + ct * 16 + n]) : 0;
        *(int4*)(Wfb + (size_t)t * 8) = *(int4*)tmp;
        return;
    }
    t -= 512;
    if (t < 2 * STATC * 32) stats[t] = 0.f;   // zero spread stats (A and B)
}

// ---------------------------------------------------------------------------
// MFMA submanifold conv, input gathered as fp32 with on-the-fly convert:
//   BN=false: a = bf16(xin[row])                (layer 0, xin = vf)
//   BN=true : a = bf16(relu(xin[row]*sc+sh))    (layer 1, xin = y0, stats0)
// Invalid tap -> zero fragment (selected after convert; BN(0) != 0).
// + BN-stat accumulation into STATC spread global copies.
// SCAT=true: grid-stride epilogue builds hidx/t2s for merge (replaces the
// scatter section of the old prep kernel). Runs first so stores overlap.
// Block = 64 voxels = 4 waves x 16; 14 steps of 16x16x32 bf16.
// y written via LDS re-tile -> coalesced full cache lines.
// ---------------------------------------------------------------------------
template<bool BN, bool SCAT>
__global__ __launch_bounds__(256)
void conv_kernel(const float* __restrict__ xin,   // [N,16] fp32
                 const unsigned short* __restrict__ Wb,   // [14*64*8] bf16
                 const int* __restrict__ nbr,     // [N,27]
                 const float* __restrict__ statsIn,  // spread stats of prev layer
                 const float* __restrict__ g, const float* __restrict__ b,
                 float invN,
                 float* __restrict__ y,           // [N,16] pre-BN out
                 float* __restrict__ statsC,      // [STATC,32]
                 const int* __restrict__ seg,
                 int* __restrict__ hidx, int* __restrict__ t2s,
                 int N)
{
    __shared__ int   sNbr[64 * 27];
    __shared__ float sY[64 * 16];
    __shared__ float sred[32];
    __shared__ float sSc[16], sSh[16];
    int tid = threadIdx.x;

    if (SCAT) {   // hidx/t2s scatter epilogue (independent; issue first)
        int t = blockIdx.x * 256 + tid;
        if (t < N) {
            hidx[seg[t]] = t;                       // injective (seg[0:N] sorted)
        } else if (t < 2 * N) {
            int r = t - N;
            int s = seg[N + r];
            if (r == 0 || seg[N + r - 1] != s) t2s[s] = r;   // run leader
        }
    }

    if (tid < 32) sred[tid] = 0.f;
    if (BN) {
        if (tid >= 32 && tid < 64) {      // reduce spread stats (other lanes)
            int c = tid - 32;
            float v = 0.f;
#pragma unroll
            for (int k = 0; k < STATC; ++k) v += statsIn[k * 32 + c];
            sY[c] = v;                    // reuse sY as scratch pre-barrier
        }
    }

    int gb = blockIdx.x * 1728;           // 64*27
    int NT = N * 27;
#pragma unroll
    for (int i = 0; i < 7; ++i) {         // 7*256 = 1792 >= 1728
        int t = i * 256 + tid;
        if (t < 1728) {
            int g2 = gb + t;
            sNbr[t] = (g2 < NT) ? __builtin_nontemporal_load(nbr + g2) : -1;
        }
    }
    __syncthreads();
    if (BN && tid < 16) {
        float mu  = sY[tid] * invN;
        float var = sY[16 + tid] * invN - mu * mu;
        float sc  = g[tid] * rsqrtf(var + BN_EPS);
        sSc[tid] = sc;
        sSh[tid] = b[tid] - mu * sc;
    }
    __syncthreads();

    int lane = tid & 63, wib = tid >> 6;
    int q = lane >> 4, m = lane & 15;
    int c0   = (q & 1) * 8;
    int tpar = q >> 1;
    int lvox = wib * 16 + m;

    float scr[8], shr[8];
    if (BN) {
#pragma unroll
        for (int j = 0; j < 8; ++j) { scr[j] = sSc[c0 + j]; shr[j] = sSh[c0 + j]; }
    }

    int idx[14];
#pragma unroll
    for (int s = 0; s < 14; ++s) {
        int tap = 2 * s + tpar;
        int id  = (tap < 27) ? sNbr[lvox * 27 + tap] : -1;
        idx[s]  = (id >= 0) ? id : N;     // N = invalid
    }

    f32x4v acc = {0.f, 0.f, 0.f, 0.f};
#pragma unroll
    for (int s = 0; s < 14; ++s) {
        int id  = idx[s];
        int rid = (id < N) ? id : 0;      // clamp addr; zero-select below
        const f32x4v* p = (const f32x4v*)(xin + (size_t)rid * 16 + c0);
        f32x4v v0 = p[0], v1 = p[1];
        unsigned short a8[8];
        if (BN) {
#pragma unroll
            for (int j = 0; j < 4; ++j) {
                a8[j]     = f2bf(fmaxf(fmaf(v0[j], scr[j],     shr[j]),     0.f));
                a8[4 + j] = f2bf(fmaxf(fmaf(v1[j], scr[4 + j], shr[4 + j]), 0.f));
            }
        } else {
#pragma unroll
            for (int j = 0; j < 4; ++j) { a8[j] = f2bf(v0[j]); a8[4 + j] = f2bf(v1[j]); }
        }
        bfrag a = *(bfrag*)a8;
        if (id >= N) a = (bfrag){0, 0, 0, 0, 0, 0, 0, 0};
        bfrag bb = *(const bfrag*)(Wb + ((size_t)s * 64 + lane) * 8);
        acc = __builtin_amdgcn_mfma_f32_16x16x32_bf16(a, bb, acc, 0, 0, 0);
    }

    int o = lane & 15;                    // out channel
#pragma unroll
    for (int i = 0; i < 4; ++i)
        sY[(wib * 16 + q * 4 + i) * 16 + o] = acc[i];

    float s  = acc[0] + acc[1] + acc[2] + acc[3];
    float qq = acc[0] * acc[0] + acc[1] * acc[1] + acc[2] * acc[2] + acc[3] * acc[3];
    s  += __shfl_xor(s, 16);  s  += __shfl_xor(s, 32);
    qq += __shfl_xor(qq, 16); qq += __shfl_xor(qq, 32);
    if (lane < 16) {
        atomicAdd(&sred[lane], s);        // LDS atomics only (4 waves)
        atomicAdd(&sred[16 + lane], qq);
    }
    __syncthreads();

    {   // coalesced y store: thread t -> row t/4, quarter t%4 (4KB contiguous)
        int row = blockIdx.x * 64 + (tid >> 2);
        if (row < N)
            *(f32x4v*)(y + (size_t)row * 16 + (tid & 3) * 4) =
                *(const f32x4v*)(sY + (size_t)(tid >> 2) * 16 + (tid & 3) * 4);
    }
    if (tid < 32)
        atomicAdd(&statsC[(blockIdx.x & (STATC - 1)) * 32 + tid], sred[tid]);
}

// ---------------------------------------------------------------------------
// Fused merge + final GEMM. Block = MBLK(128) output slots, 256 threads.
// Phase 0: reduce spread stats -> BN coeffs in LDS.
// Phase 1 (ALL 256 threads, thread = slot x half): merged row =
//   relu(bn1(y1[hidx[u]])) + (bobo + sum_{run} feat2[r] @ Wobo).
// Phase 2 (4 waves x 2 row-tiles): merged[128,16] @ Wf via mfma, +bf,
//   plain stores (L2 merges the 8 ct segments into full lines).
// ---------------------------------------------------------------------------
__global__ __launch_bounds__(256)
void merge_final_kernel(const float* __restrict__ y1, const float* __restrict__ statsC,
                        const float* __restrict__ g, const float* __restrict__ b,
                        float invN,
                        const float* __restrict__ feat2, const float* __restrict__ Wobo,
                        const float* __restrict__ bobo,
                        const int* __restrict__ seg,
                        const int* __restrict__ hidx, const int* __restrict__ t2s,
                        const unsigned short* __restrict__ Wfb,
                        const float* __restrict__ bf,
                        float* __restrict__ out, int N, int U)
{
    __shared__ unsigned short smA[MBLK * 16];   // merged tile, bf16 (4KB)
    __shared__ float sred[32];
    __shared__ float sSc[16], sSh[16];
    int tid = threadIdx.x;
    int u0  = blockIdx.x * MBLK;

    if (tid < 32) {
        float v = 0.f;
#pragma unroll
        for (int k = 0; k < STATC; ++k) v += statsC[k * 32 + tid];
        sred[tid] = v;
    }
    __syncthreads();
    if (tid < 16) {
        float mu  = sred[tid] * invN;
        float var = sred[16 + tid] * invN - mu * mu;
        float sc  = g[tid] * rsqrtf(var + BN_EPS);
        sSc[tid] = sc;
        sSh[tid] = b[tid] - mu * sc;
    }
    __syncthreads();

    {   // phase 1: all 256 threads; thread = slot x half
        int sl = tid >> 1, half = tid & 1;
        int u  = u0 + sl;
        bool valid = u < U;
        int uc = valid ? u : 0;
        int hi = hidx[uc];                 // independent loads, issue together
        int r  = t2s[uc];
        bool hasH = valid && (unsigned)hi < (unsigned)N && seg[hi] == u;
        bool hasT = valid && (unsigned)r  < (unsigned)N && seg[N + r] == u;

        // hoisted unconditional data loads (clamped addresses, masked use)
        size_t hoff = (size_t)(hasH ? hi : 0) * 16 + half * 8;
        f32x4v yv0 = *(const f32x4v*)(y1 + hoff);
        f32x4v yv1 = *(const f32x4v*)(y1 + hoff + 4);
        size_t toff = (size_t)(hasT ? r : 0) * 16;
        f32x4v f0 = __builtin_nontemporal_load((const f32x4v*)(feat2 + toff));
        f32x4v f1 = __builtin_nontemporal_load((const f32x4v*)(feat2 + toff) + 1);
        f32x4v f2 = __builtin_nontemporal_load((const f32x4v*)(feat2 + toff) + 2);
        f32x4v f3 = __builtin_nontemporal_load((const f32x4v*)(feat2 + toff) + 3);

        float m[8];
#pragma unroll
        for (int j = 0; j < 8; ++j) m[j] = 0.f;
        if (hasH) {
#pragma unroll
            for (int j = 0; j < 4; ++j) {
                int c = half * 8 + j;
                m[j]     = fmaxf(fmaf(yv0[j], sSc[c],     sSh[c]),     0.f);
                m[4 + j] = fmaxf(fmaf(yv1[j], sSc[c + 4], sSh[c + 4]), 0.f);
            }
        }
        if (hasT) {
            float a2[8];
#pragma unroll
            for (int j = 0; j < 8; ++j) a2[j] = bobo[half * 8 + j];
            float fv[16];
            *(f32x4v*)(fv + 0)  = f0; *(f32x4v*)(fv + 4)  = f1;
            *(f32x4v*)(fv + 8)  = f2; *(f32x4v*)(fv + 12) = f3;
            for (;;) {
#pragma unroll
                for (int c = 0; c < 16; ++c) {
                    float xc = fv[c];
                    const float* wr = Wobo + c * 16 + half * 8;  // L1-hot
#pragma unroll
                    for (int j = 0; j < 8; ++j) a2[j] = fmaf(xc, wr[j], a2[j]);
                }
                ++r;
                if (r >= N || seg[N + r] != u) break;
                const f32x4v* fr = (const f32x4v*)(feat2 + (size_t)r * 16);
                f32x4v g0 = __builtin_nontemporal_load(fr);
                f32x4v g1 = __builtin_nontemporal_load(fr + 1);
                f32x4v g2 = __builtin_nontemporal_load(fr + 2);
                f32x4v g3 = __builtin_nontemporal_load(fr + 3);
                *(f32x4v*)(fv + 0)  = g0; *(f32x4v*)(fv + 4)  = g1;
                *(f32x4v*)(fv + 8)  = g2; *(f32x4v*)(fv + 12) = g3;
            }
#pragma unroll
            for (int j = 0; j < 8; ++j) m[j] += a2[j];
        }
        unsigned short tb[8];
#pragma unroll
        for (int j = 0; j < 8; ++j) tb[j] = f2bf(m[j]);
        *(int4*)(smA + (size_t)tid * 8) = *(int4*)tb;   // slot*16 + half*8
    }
    __syncthreads();

    int lane = tid & 63, w = tid >> 6;
    int q = lane >> 4, n = lane & 15;
#pragma unroll
    for (int rt = 0; rt < 2; ++rt) {      // wave w: rows w*32 + rt*16 .. +15
        int row0 = w * 32 + rt * 16;
        bfrag a = {0, 0, 0, 0, 0, 0, 0, 0};
        if (q < 2)
            a = *(const bfrag*)(smA + ((size_t)(row0 + n) * 16 + q * 8));
#pragma unroll
        for (int ct = 0; ct < 8; ++ct) {
            bfrag bb = *(const bfrag*)(Wfb + ((size_t)(ct * 64 + lane)) * 8);
            f32x4v acc = {0.f, 0.f, 0.f, 0.f};
            acc = __builtin_amdgcn_mfma_f32_16x16x32_bf16(a, bb, acc, 0, 0, 0);
            int col = ct * 16 + n;
            float bv = bf[col];
#pragma unroll
            for (int i = 0; i < 4; ++i) {
                int u = u0 + row0 + q * 4 + i;
                if (u < U) out[(size_t)u * 128 + col] = acc[i] + bv;  // plain: L2 merges
            }
        }
    }
}

extern "C" void kernel_launch(void* const* d_in, const int* in_sizes, int n_in,
                              void* d_out, int out_size, void* d_ws, size_t ws_size,
                              hipStream_t stream)
{
    const float* vf    = (const float*)d_in[0];
    const float* feat2 = (const float*)d_in[1];
    const float* W0    = (const float*)d_in[2];
    const float* g0    = (const float*)d_in[3];
    const float* b0    = (const float*)d_in[4];
    const float* W1    = (const float*)d_in[5];
    const float* g1    = (const float*)d_in[6];
    const float* b1    = (const float*)d_in[7];
    const float* Wobo  = (const float*)d_in[8];
    const float* bobo  = (const float*)d_in[9];
    const float* Wf    = (const float*)d_in[10];
    const float* bf    = (const float*)d_in[11];
    const int*   nbr   = (const int*)d_in[12];
    const int*   seg   = (const int*)d_in[13];

    int N = in_sizes[0] / 16;   // 100000
    int U = out_size / 128;     // num_segments

    float* out = (float*)d_out;
    float* ws  = (float*)d_ws;

    int gbConv = (N + 63) / 64;

    // Workspace (float units):
    float* y0     = ws;                                  // N*16
    float* y1     = y0 + (size_t)N * 16;                 // N*16
    float* statsA = y1 + (size_t)N * 16;                 // STATC*32 (conv1)
    float* statsB = statsA + STATC * 32;                 // STATC*32 (conv2)
    unsigned short* Wb0 = (unsigned short*)(statsB + STATC * 32);  // 14*64*8
    unsigned short* Wb1 = Wb0 + 14 * 64 * 8;             // 14*64*8
    unsigned short* Wfb = Wb1 + 14 * 64 * 8;             // 8*64*8
    int* hidx = (int*)(Wfb + 8 * 64 * 8);                // U
    int* t2s  = hidx + U;                                // U

    float invN  = 1.f / (float)N;
    int gbPrep  = (2 * 14 * 64 + 512 + 2 * STATC * 32 + 255) / 256;
    int gbMerge = (U + MBLK - 1) / MBLK;

    prep_kernel<<<gbPrep, 256, 0, stream>>>(W0, W1, Wf, Wb0, Wb1, Wfb, statsA);
    conv_kernel<false, true><<<gbConv, 256, 0, stream>>>(
        vf, Wb0, nbr, nullptr, nullptr, nullptr, 0.f,
        y0, statsA, seg, hidx, t2s, N);
    conv_kernel<true, false><<<gbConv, 256, 0, stream>>>(
        y0, Wb1, nbr, statsA, g0, b0, invN,
        y1, statsB, seg, nullptr, nullptr, N);
    merge_final_kernel<<<gbMerge, 256, 0, stream>>>(y1, statsB, g1, b1, invN,
                                                    feat2, Wobo, bobo, seg,
                                                    hidx, t2s, Wfb, bf, out, N, U);
}

// Round 7
// 149.993 us; speedup vs baseline: 1.1879x; 1.1879x over previous
//
#include <hip/hip_runtime.h>

#define BN_EPS 1e-3f
#define STATC  32   // spread copies for the stats atomics
#define MBLK   128  // merge tile: slots per block

using bfrag  = __attribute__((ext_vector_type(8))) short;  // 8 bf16 (4 VGPRs)
using f32x4v = __attribute__((ext_vector_type(4))) float;  // native vec for NT builtins
using i32x4v = __attribute__((ext_vector_type(4))) int;

__device__ __forceinline__ unsigned short f2bf(float f) {
    union { float f; unsigned u; } v; v.f = f;
    unsigned r = v.u + 0x7FFFu + ((v.u >> 16) & 1u);   // RNE
    return (unsigned short)(r >> 16);
}

// ---------------------------------------------------------------------------
// Prep, thread ranges:
//  A: vf [N,16] fp32 -> xb0 [(N+1),16] bf16 (row N = zeros)
//  W: W0/W1 [27,16,16] -> Wb0/Wb1 MFMA B-frag order (14 K-steps)
//  F: Wf [16,128] -> Wfb B-frag order (8 col-tiles, K=16 padded to 32)
//  Z: zero 2*STATC*32 spread stat accumulators
//  H: hidx[seg[r]] = r            (h contributor per slot; injective)
//  T: t2s[seg[N+r]] = r for run leaders (seg[N:2N] non-decreasing)
// ---------------------------------------------------------------------------
__global__ __launch_bounds__(256)
void prep_kernel(const float* __restrict__ vf,
                 const float* __restrict__ W0, const float* __restrict__ W1,
                 const float* __restrict__ Wf, const int* __restrict__ seg,
                 unsigned short* __restrict__ xb0,
                 unsigned short* __restrict__ Wb0, unsigned short* __restrict__ Wb1,
                 unsigned short* __restrict__ Wfb,
                 float* __restrict__ stats,
                 int* __restrict__ hidx, int* __restrict__ t2s, int N)
{
    int t = blockIdx.x * 256 + threadIdx.x;
    int TA = 2 * (N + 1);
    unsigned short tmp[8];
    if (t < TA) {                         // xb0
        int n = t >> 1, h = t & 1;
        if (n < N) {
            const f32x4v* yr = (const f32x4v*)(vf + (size_t)n * 16 + h * 8);
            f32x4v v0 = __builtin_nontemporal_load(yr);
            f32x4v v1 = __builtin_nontemporal_load(yr + 1);
#pragma unroll
            for (int j = 0; j < 4; ++j) { tmp[j] = f2bf(v0[j]); tmp[4 + j] = f2bf(v1[j]); }
        } else {
#pragma unroll
            for (int j = 0; j < 8; ++j) tmp[j] = 0;
        }
        *(int4*)(xb0 + (size_t)n * 16 + h * 8) = *(int4*)tmp;
        return;
    }
    t -= TA;
    if (t < 2 * 14 * 64) {                // Wb0 / Wb1
        int w = t >= 896;
        int l = t - w * 896;
        int s = l >> 6, lane = l & 63;
        int q = lane >> 4, n = lane & 15;
        int tap = 2 * s + (q >> 1);
        int cb  = (q & 1) * 8;
        const float* W = w ? W1 : W0;
        unsigned short* Wb = w ? Wb1 : Wb0;
#pragma unroll
        for (int j = 0; j < 8; ++j)
            tmp[j] = (tap < 27) ? f2bf(W[((size_t)(tap * 16 + cb + j)) * 16 + n]) : 0;
        *(int4*)(Wb + (size_t)l * 8) = *(int4*)tmp;
        return;
    }
    t -= 2 * 14 * 64;
    if (t < 512) {                        // Wfb: B[k=q*8+j][ct*16+n], k>=16 -> 0
        int ct = t >> 6, lane = t & 63;
        int q = lane >> 4, n = lane & 15;
#pragma unroll
        for (int j = 0; j < 8; ++j)
            tmp[j] = (q < 2) ? f2bf(Wf[(size_t)(q * 8 + j) * 128 + ct * 16 + n]) : 0;
        *(int4*)(Wfb + (size_t)t * 8) = *(int4*)tmp;
        return;
    }
    t -= 512;
    if (t < 2 * STATC * 32) { stats[t] = 0.f; return; }   // zero spread stats
    t -= 2 * STATC * 32;
    if (t < N) { hidx[seg[t]] = t; return; }
    t -= N;
    if (t < N) {
        int s = seg[N + t];
        if (t == 0 || seg[N + t - 1] != s) t2s[s] = t;   // run leader
    }
}

// ---------------------------------------------------------------------------
// MFMA submanifold conv + BN-stat accumulation into STATC spread global
// copies. Block = 64 voxels = 4 waves x 16. nbr slab staged via int4
// nontemporal vector loads (432 x 16B). 14 steps of 16x16x32 bf16.
// y written via LDS re-tile -> coalesced full cache lines.
// ---------------------------------------------------------------------------
__global__ __launch_bounds__(256)
void conv_stats_kernel(const unsigned short* __restrict__ xb,  // [(N+1),16] bf16
                       const unsigned short* __restrict__ Wb,  // [14*64*8] bf16
                       const int* __restrict__ nbr,            // [N,27]
                       float* __restrict__ y,                  // [N,16] pre-BN
                       float* __restrict__ statsC,             // [STATC,32]
                       int N)
{
    __shared__ __align__(16) int   sNbr[64 * 27];
    __shared__ __align__(16) float sY[64 * 16];
    __shared__ float sred[32];
    int tid = threadIdx.x;
    if (tid < 32) sred[tid] = 0.f;

    int gb = blockIdx.x * 1728;           // 64*27
    int NT = N * 27;
    if (gb + 1728 <= NT) {                // full tile: 432 x int4 vector loads
#pragma unroll
        for (int i = 0; i < 2; ++i) {
            int t4 = i * 256 + tid;
            if (t4 < 432) {
                i32x4v v = __builtin_nontemporal_load((const i32x4v*)(nbr + gb) + t4);
                *(i32x4v*)(sNbr + t4 * 4) = v;
            }
        }
    } else {                              // tail block: scalar guarded
#pragma unroll
        for (int i = 0; i < 7; ++i) {
            int t = i * 256 + tid;
            if (t < 1728) {
                int g2 = gb + t;
                sNbr[t] = (g2 < NT) ? __builtin_nontemporal_load(nbr + g2) : -1;
            }
        }
    }
    __syncthreads();

    int lane = tid & 63, wib = tid >> 6;
    int q = lane >> 4, m = lane & 15;
    int c0   = (q & 1) * 8;
    int tpar = q >> 1;
    int lvox = wib * 16 + m;

    int idx[14];
#pragma unroll
    for (int s = 0; s < 14; ++s) {
        int tap = 2 * s + tpar;
        int id  = (tap < 27) ? sNbr[lvox * 27 + tap] : -1;
        idx[s]  = (id >= 0) ? id : N;     // row N = zeros
    }

    f32x4v acc = {0.f, 0.f, 0.f, 0.f};
#pragma unroll
    for (int s = 0; s < 14; ++s) {
        bfrag a = *(const bfrag*)(xb + (size_t)idx[s] * 16 + c0);
        bfrag b = *(const bfrag*)(Wb + ((size_t)s * 64 + lane) * 8);
        acc = __builtin_amdgcn_mfma_f32_16x16x32_bf16(a, b, acc, 0, 0, 0);
    }

    int o = lane & 15;                    // out channel
#pragma unroll
    for (int i = 0; i < 4; ++i)
        sY[(wib * 16 + q * 4 + i) * 16 + o] = acc[i];

    float s  = acc[0] + acc[1] + acc[2] + acc[3];
    float qq = acc[0] * acc[0] + acc[1] * acc[1] + acc[2] * acc[2] + acc[3] * acc[3];
    s  += __shfl_xor(s, 16);  s  += __shfl_xor(s, 32);
    qq += __shfl_xor(qq, 16); qq += __shfl_xor(qq, 32);
    if (lane < 16) {
        atomicAdd(&sred[lane], s);        // LDS atomics only (4 waves)
        atomicAdd(&sred[16 + lane], qq);
    }
    __syncthreads();

    {   // coalesced y store: thread t -> row t/4, quarter t%4 (4KB contiguous)
        int row = blockIdx.x * 64 + (tid >> 2);
        if (row < N)
            *(f32x4v*)(y + (size_t)row * 16 + (tid & 3) * 4) =
                *(const f32x4v*)(sY + (size_t)(tid >> 2) * 16 + (tid & 3) * 4);
    }
    if (tid < 32)
        atomicAdd(&statsC[(blockIdx.x & (STATC - 1)) * 32 + tid], sred[tid]);
}

// ---------------------------------------------------------------------------
// xb1[n] = bf16(relu(y0[n]*sc+sh)), row N = zeros. BN coeffs reduced from
// the STATC spread copies once per block (L2-hot). Thread = 8 channels.
// ---------------------------------------------------------------------------
__global__ __launch_bounds__(256)
void bnrelu_cvt_kernel(const float* __restrict__ y0, const float* __restrict__ statsC,
                       const float* __restrict__ g, const float* __restrict__ b,
                       float invN, unsigned short* __restrict__ xb, int N)
{
    __shared__ float sred[32];
    __shared__ float sSc[16], sSh[16];
    int tid = threadIdx.x;
    if (tid < 32) {
        float v = 0.f;
#pragma unroll
        for (int k = 0; k < STATC; ++k) v += statsC[k * 32 + tid];
        sred[tid] = v;
    }
    __syncthreads();
    if (tid < 16) {
        float mu  = sred[tid] * invN;
        float var = sred[16 + tid] * invN - mu * mu;
        float sc  = g[tid] * rsqrtf(var + BN_EPS);
        sSc[tid] = sc;
        sSh[tid] = b[tid] - mu * sc;
    }
    __syncthreads();

    int t = blockIdx.x * 256 + tid;
    if (t >= (N + 1) * 2) return;
    int n = t >> 1, h = t & 1;
    unsigned short tmp[8];
    if (n < N) {
        const f32x4v* yr4 = (const f32x4v*)(y0 + (size_t)n * 16 + h * 8);
        f32x4v v0 = __builtin_nontemporal_load(yr4);
        f32x4v v1 = __builtin_nontemporal_load(yr4 + 1);
#pragma unroll
        for (int j = 0; j < 4; ++j) {
            int c = h * 8 + j;
            tmp[j]     = f2bf(fmaxf(fmaf(v0[j], sSc[c], sSh[c]), 0.f));
            tmp[4 + j] = f2bf(fmaxf(fmaf(v1[j], sSc[c + 4], sSh[c + 4]), 0.f));
        }
    } else {
#pragma unroll
        for (int j = 0; j < 8; ++j) tmp[j] = 0;
    }
    *(int4*)(xb + (size_t)n * 16 + h * 8) = *(int4*)tmp;
}

// ---------------------------------------------------------------------------
// Fused merge + final GEMM. Block = MBLK(128) output slots, 256 threads.
// Phase 0: reduce spread stats -> BN coeffs in LDS.
// Phase 1 (ALL 256 threads, thread = slot x half): merged row =
//   relu(bn1(y1[hidx[u]])) + MLP(sum_{run} feat2[r]).
//   Sum-then-MLP: run loop only sums 16 floats/row; the 16x16 Wobo MLP
//   runs ONCE per run (linearity of segment_sum o matmul).
// Phase 2 (4 waves x 2 row-tiles): merged[128,16] @ Wf via mfma, +bf,
//   plain stores (L2 merges the 8 ct segments into full lines).
// ---------------------------------------------------------------------------
__global__ __launch_bounds__(256)
void merge_final_kernel(const float* __restrict__ y1, const float* __restrict__ statsC,
                        const float* __restrict__ g, const float* __restrict__ b,
                        float invN,
                        const float* __restrict__ feat2, const float* __restrict__ Wobo,
                        const float* __restrict__ bobo,
                        const int* __restrict__ seg,
                        const int* __restrict__ hidx, const int* __restrict__ t2s,
                        const unsigned short* __restrict__ Wfb,
                        const float* __restrict__ bf,
                        float* __restrict__ out, int N, int U)
{
    __shared__ unsigned short smA[MBLK * 16];   // merged tile, bf16 (4KB)
    __shared__ float sred[32];
    __shared__ float sSc[16], sSh[16];
    int tid = threadIdx.x;
    int u0  = blockIdx.x * MBLK;

    if (tid < 32) {
        float v = 0.f;
#pragma unroll
        for (int k = 0; k < STATC; ++k) v += statsC[k * 32 + tid];
        sred[tid] = v;
    }
    __syncthreads();
    if (tid < 16) {
        float mu  = sred[tid] * invN;
        float var = sred[16 + tid] * invN - mu * mu;
        float sc  = g[tid] * rsqrtf(var + BN_EPS);
        sSc[tid] = sc;
        sSh[tid] = b[tid] - mu * sc;
    }
    __syncthreads();

    {   // phase 1: all 256 threads; thread = slot x half
        int sl = tid >> 1, half = tid & 1;
        int u  = u0 + sl;
        bool valid = u < U;
        int uc = valid ? u : 0;
        int hi = hidx[uc];                 // independent loads, issue together
        int r  = t2s[uc];
        bool hasH = valid && (unsigned)hi < (unsigned)N && seg[hi] == u;
        bool hasT = valid && (unsigned)r  < (unsigned)N && seg[N + r] == u;

        // hoisted unconditional h load (clamped address, masked use)
        size_t hoff = (size_t)(hasH ? hi : 0) * 16 + half * 8;
        f32x4v yv0 = *(const f32x4v*)(y1 + hoff);
        f32x4v yv1 = *(const f32x4v*)(y1 + hoff + 4);

        float m[8];
#pragma unroll
        for (int j = 0; j < 8; ++j) m[j] = 0.f;
        if (hasH) {
#pragma unroll
            for (int j = 0; j < 4; ++j) {
                int c = half * 8 + j;
                m[j]     = fmaxf(fmaf(yv0[j], sSc[c],     sSh[c]),     0.f);
                m[4 + j] = fmaxf(fmaf(yv1[j], sSc[c + 4], sSh[c + 4]), 0.f);
            }
        }
        if (hasT) {
            float S[16];
#pragma unroll
            for (int c = 0; c < 16; ++c) S[c] = 0.f;
            do {    // run loop: only sums (16 adds/row)
                const f32x4v* fr = (const f32x4v*)(feat2 + (size_t)r * 16);
                f32x4v f0 = __builtin_nontemporal_load(fr);
                f32x4v f1 = __builtin_nontemporal_load(fr + 1);
                f32x4v f2 = __builtin_nontemporal_load(fr + 2);
                f32x4v f3 = __builtin_nontemporal_load(fr + 3);
#pragma unroll
                for (int c = 0; c < 4; ++c) {
                    S[c] += f0[c]; S[4 + c] += f1[c];
                    S[8 + c] += f2[c]; S[12 + c] += f3[c];
                }
                ++r;
            } while (r < N && seg[N + r] == u);
            float a2[8];
#pragma unroll
            for (int j = 0; j < 8; ++j) a2[j] = bobo[half * 8 + j];
#pragma unroll
            for (int c = 0; c < 16; ++c) {    // MLP once per run
                float xc = S[c];
                const float* wr = Wobo + c * 16 + half * 8;  // L1-hot
#pragma unroll
                for (int j = 0; j < 8; ++j) a2[j] = fmaf(xc, wr[j], a2[j]);
            }
#pragma unroll
            for (int j = 0; j < 8; ++j) m[j] += a2[j];
        }
        unsigned short tb[8];
#pragma unroll
        for (int j = 0; j < 8; ++j) tb[j] = f2bf(m[j]);
        *(int4*)(smA + (size_t)tid * 8) = *(int4*)tb;   // slot*16 + half*8
    }
    __syncthreads();

    int lane = tid & 63, w = tid >> 6;
    int q = lane >> 4, n = lane & 15;
#pragma unroll
    for (int rt = 0; rt < 2; ++rt) {      // wave w: rows w*32 + rt*16 .. +15
        int row0 = w * 32 + rt * 16;
        bfrag a = {0, 0, 0, 0, 0, 0, 0, 0};
        if (q < 2)
            a = *(const bfrag*)(smA + ((size_t)(row0 + n) * 16 + q * 8));
#pragma unroll
        for (int ct = 0; ct < 8; ++ct) {
            bfrag bb = *(const bfrag*)(Wfb + ((size_t)(ct * 64 + lane)) * 8);
            f32x4v acc = {0.f, 0.f, 0.f, 0.f};
            acc = __builtin_amdgcn_mfma_f32_16x16x32_bf16(a, bb, acc, 0, 0, 0);
            int col = ct * 16 + n;
            float bv = bf[col];
#pragma unroll
            for (int i = 0; i < 4; ++i) {
                int u = u0 + row0 + q * 4 + i;
                if (u < U) out[(size_t)u * 128 + col] = acc[i] + bv;  // plain: L2 merges
            }
        }
    }
}

extern "C" void kernel_launch(void* const* d_in, const int* in_sizes, int n_in,
                              void* d_out, int out_size, void* d_ws, size_t ws_size,
                              hipStream_t stream)
{
    const float* vf    = (const float*)d_in[0];
    const float* feat2 = (const float*)d_in[1];
    const float* W0    = (const float*)d_in[2];
    const float* g0    = (const float*)d_in[3];
    const float* b0    = (const float*)d_in[4];
    const float* W1    = (const float*)d_in[5];
    const float* g1    = (const float*)d_in[6];
    const float* b1    = (const float*)d_in[7];
    const float* Wobo  = (const float*)d_in[8];
    const float* bobo  = (const float*)d_in[9];
    const float* Wf    = (const float*)d_in[10];
    const float* bf    = (const float*)d_in[11];
    const int*   nbr   = (const int*)d_in[12];
    const int*   seg   = (const int*)d_in[13];

    int N = in_sizes[0] / 16;   // 100000
    int U = out_size / 128;     // num_segments

    float* out = (float*)d_out;
    float* ws  = (float*)d_ws;

    int gbConv = (N + 63) / 64;

    // Workspace (float units):
    float* y0     = ws;                                  // N*16
    float* y1     = y0 + (size_t)N * 16;                 // N*16
    float* statsA = y1 + (size_t)N * 16;                 // STATC*32 (conv1)
    float* statsB = statsA + STATC * 32;                 // STATC*32 (conv2)
    unsigned short* xb0 = (unsigned short*)(statsB + STATC * 32);
    unsigned short* xb1 = xb0 + (size_t)(N + 1) * 16;    // (N+1)*16
    unsigned short* Wb0 = xb1 + (size_t)(N + 1) * 16;    // 14*64*8
    unsigned short* Wb1 = Wb0 + 14 * 64 * 8;             // 14*64*8
    unsigned short* Wfb = Wb1 + 14 * 64 * 8;             // 8*64*8
    int* hidx = (int*)(Wfb + 8 * 64 * 8);                // U
    int* t2s  = hidx + U;                                // U

    float invN  = 1.f / (float)N;
    int thrPrep = 2 * (N + 1) + 2 * 14 * 64 + 512 + 2 * STATC * 32 + 2 * N;
    int gbPrep  = (thrPrep + 255) / 256;
    int gbCvt   = ((N + 1) * 2 + 255) / 256;
    int gbMerge = (U + MBLK - 1) / MBLK;

    prep_kernel<<<gbPrep, 256, 0, stream>>>(vf, W0, W1, Wf, seg, xb0, Wb0, Wb1,
                                            Wfb, statsA, hidx, t2s, N);
    conv_stats_kernel<<<gbConv, 256, 0, stream>>>(xb0, Wb0, nbr, y0, statsA, N);
    bnrelu_cvt_kernel<<<gbCvt, 256, 0, stream>>>(y0, statsA, g0, b0, invN, xb1, N);
    conv_stats_kernel<<<gbConv, 256, 0, stream>>>(xb1, Wb1, nbr, y1, statsB, N);
    merge_final_kernel<<<gbMerge, 256, 0, stream>>>(y1, statsB, g1, b1, invN,
                                                    feat2, Wobo, bobo, seg,
                                                    hidx, t2s, Wfb, bf, out, N, U);
}